// Round 2
// baseline (2794.711 us; speedup 1.0000x reference)
//
#include <hip/hip_runtime.h>
#include <hip/hip_bf16.h>

#define SEQT 2000
#define NB   2048
#define H1   51
#define MROW 16
#define NBLK (NB / MROW)   // 128 blocks
#define PADK 328           // shorts per staged row (656 B = 41*16, 16B-aligned)

typedef float f32x4 __attribute__((ext_vector_type(4)));
typedef short s16x8 __attribute__((ext_vector_type(8)));

__device__ __forceinline__ short f2bf(float f) { __hip_bfloat16 b(f); return *(short*)&b; }
__device__ __forceinline__ float bf2f(short s) { __hip_bfloat16 b; *(short*)&b = s; return (float)b; }
__device__ __forceinline__ float rbf(float f) { return bf2f(f2bf(f)); }
__device__ __forceinline__ float fastrcp(float x) { return __builtin_amdgcn_rcpf(x); }
__device__ __forceinline__ float sigf(float x) { return fastrcp(1.f + __expf(-x)); }
__device__ __forceinline__ float tanhfast(float x) { return 1.f - 2.f * fastrcp(__expf(2.f * x) + 1.f); }

// RNE f32->bf16 (bit trick; values are finite so no NaN path needed)
__device__ __forceinline__ unsigned rne_bf16(float v) {
    unsigned b = __float_as_uint(v);
    return (b + 0x7fffu + ((b >> 16) & 1u)) >> 16;
}
// packed (hi | lo<<16), both RNE — numerically identical to the f2bf/bf2f path
__device__ __forceinline__ unsigned pack_hilo(float v) {
    const unsigned hh = rne_bf16(v);
    const float hi = __uint_as_float(hh << 16);
    const unsigned hl = rne_bf16(v - hi);
    return hh | (hl << 16);
}

__device__ __forceinline__ f32x4 mfma16(s16x8 a, s16x8 b, f32x4 c) {
    return __builtin_amdgcn_mfma_f32_16x16x32_bf16(a, b, c, 0, 0, 0);
}

// B-side (staged vector) column map, K=320 (10 k-tiles of 32):
//   2u/2u+1 (u<51): h_hi/h_lo      | A: Whh_hi[n][u] (both)
//   102+u   (u<51): h_hi           | A: Whh_lo[n][u]
//   153: x_hi  154: x_lo  155: x_hi| A: Wih_hi, Wih_hi, Wih_lo
//   156: 1.0   157: 1.0            | A: bias_hi, bias_lo
//   158,159: 0
//   160+2u/161+2u (u<51): c1_hi/c1_lo | A(z rows g): W3_hi[g][u] (both)
//   262+u   (u<51): c1_hi             | A(z): W3_lo[g][u]
//   313..319: 0   320..327: write scratch (never read)
// Gate rows n' = u*4+g (13 N-tiles). MFMA A=weights, B=staged vector.
// C/D: col(lane&15)=m, row(quad*4+reg)=n' -> lane (kq,iloc) holds all 4 gates
// of unit u = tile*4+kq for batch row m = iloc.
//
// 8-wave layout (512 thr): w0..w5 -> tiles {2w,2w+1}; w6 -> tile 12;
// w7 -> z-MFMA + LSTM3 + x-staging + Xbuf chunk fills. SIMD pairing
// (wave i on SIMD i%4): SIMD0/1 carry 4 tiles, SIMD2 3 tiles+?, SIMD3
// 2 tiles + the serial LSTM3 chain -> two streams per SIMD hide stalls.

template <int I0, int NTc>
__device__ __forceinline__ void run_tiles(const s16x8 (&Wfr)[2][5], const s16x8 (&hf)[5],
                                          float (&c1st)[2], short* __restrict__ Hw,
                                          const int iloc, const int kq) {
    f32x4 acc[2];
#pragma unroll
    for (int i = 0; i < NTc; ++i) {
        f32x4 a0 = {0.f, 0.f, 0.f, 0.f};
        f32x4 a1 = {0.f, 0.f, 0.f, 0.f};
        a0 = mfma16(Wfr[i][0], hf[0], a0);
        a1 = mfma16(Wfr[i][1], hf[1], a1);
        a0 = mfma16(Wfr[i][2], hf[2], a0);
        a1 = mfma16(Wfr[i][3], hf[3], a1);
        a0 = mfma16(Wfr[i][4], hf[4], a0);
        acc[i] = a0 + a1;
    }
#pragma unroll
    for (int i = 0; i < NTc; ++i) {
        const int u = (I0 + i) * 4 + kq;
        const int m = iloc;
        float c1 = c1st[i];
        c1 = sigf(acc[i][1]) * c1 + sigf(acc[i][0]) * tanhfast(acc[i][2]);
        c1st[i] = c1;
        const float h1 = sigf(acc[i][3]) * tanhfast(c1);
        const bool ok = (u < H1);
        const int base = m * PADK;
        const unsigned hp = pack_hilo(h1);
        const unsigned cp = pack_hilo(c1);
        *(unsigned*)&Hw[base + (ok ? 2 * u : 320)] = hp;
        Hw[base + (ok ? 102 + u : 322)] = (short)hp;
        *(unsigned*)&Hw[base + (ok ? 160 + 2 * u : 324)] = cp;
        Hw[base + (ok ? 262 + u : 326)] = (short)cp;
    }
}

// Fill one 64-step x-chunk into Xbuf (one wave, all 64 lanes).
__device__ __forceinline__ void xchunk_fill(const float* __restrict__ input, int r0, int c,
                                            int lane, unsigned (*Xb)[64 * 16]) {
    const int m = lane & 15, q = lane >> 4;
    const int tt = c * 64 + q * 16;
    f32x4 v[4];
    if (tt < SEQT) {
        const float* src = input + (size_t)(r0 + m) * SEQT + tt;
#pragma unroll
        for (int p = 0; p < 4; ++p) v[p] = *(const f32x4*)(src + 4 * p);
    } else {
#pragma unroll
        for (int p = 0; p < 4; ++p) v[p] = (f32x4){0.f, 0.f, 0.f, 0.f};
    }
#pragma unroll
    for (int p = 0; p < 4; ++p)
#pragma unroll
        for (int j = 0; j < 4; ++j)
            Xb[c & 1][(q * 16 + p * 4 + j) * 16 + m] = pack_hilo(v[p][j]);
}

__global__ void __launch_bounds__(512)
__attribute__((amdgpu_waves_per_eu(2)))
lstm_fused_kernel(const float* __restrict__ input,
                  const float* __restrict__ W_ih1,
                  const float* __restrict__ W_hh1,
                  const float* __restrict__ b_ih1,
                  const float* __restrict__ b_hh1,
                  const float* __restrict__ W_ih3,
                  const float* __restrict__ W_hh3,
                  const float* __restrict__ b_ih3,
                  const float* __restrict__ b_hh3,
                  float* __restrict__ out) {
    const int t = threadIdx.x;
    const int w = t >> 6;          // wave 0..7
    const int lane = t & 63;
    const int iloc = lane & 15, kq = lane >> 4;
    const int r0 = blockIdx.x * MROW;

    __shared__ short Hst[2][MROW * PADK];      // staged vector rows, parity dbuf
    __shared__ float Obuf[2][MROW * 64];       // c3 chunks
    __shared__ unsigned Xbuf[2][64 * 16];      // packed x hi/lo, 64-step chunks

    // tile assignment: w0..w5 -> 2 tiles, w6 -> 1 tile, w7 -> none (z/LSTM3/x)
    const int NT = (w < 6) ? 2 : (w == 6) ? 1 : 0;
    const int tb = 2 * w;   // valid for w <= 6

    // ---- gate-row weight fragments (A-operand) ----
    s16x8 Wfr[2][5];
#pragma unroll
    for (int i = 0; i < 2; ++i) {
        if (i < NT) {
            const int np = (tb + i) * 16 + iloc;
            const int u = np >> 2, g = np & 3;
            const int n = g * H1 + u;
#pragma unroll
            for (int kt = 0; kt < 5; ++kt) {
                s16x8 bf;
#pragma unroll
                for (int j = 0; j < 8; ++j) {
                    const int k = kt * 32 + kq * 8 + j;
                    float v = 0.f;
                    if (u < H1) {
                        if (k < 102) {
                            v = rbf(W_hh1[n * H1 + (k >> 1)]);
                        } else if (k < 153) {
                            const float wv = W_hh1[n * H1 + (k - 102)];
                            v = wv - rbf(wv);
                        } else if (k == 153 || k == 154) {
                            v = rbf(W_ih1[n]);
                        } else if (k == 155) {
                            const float wv = W_ih1[n];
                            v = wv - rbf(wv);
                        } else if (k == 156) {
                            v = rbf(b_ih1[n] + b_hh1[n]);
                        } else if (k == 157) {
                            const float bv = b_ih1[n] + b_hh1[n];
                            v = bv - rbf(bv);
                        }
                    }
                    bf[j] = f2bf(v);
                }
                Wfr[i][kt] = bf;
            }
        }
    }

    // ---- z-tile A fragments (wave 7): rows g=0..3 = W_ih3 hi/lo ----
    s16x8 Zfr[5];
    if (w == 7) {
        const int g = iloc;
#pragma unroll
        for (int kt = 0; kt < 5; ++kt) {
            s16x8 bf;
#pragma unroll
            for (int j = 0; j < 8; ++j) {
                const int kz = kt * 32 + kq * 8 + j;   // col - 160
                float v = 0.f;
                if (iloc < 4) {
                    if (kz < 102) {
                        v = rbf(W_ih3[g * H1 + (kz >> 1)]);
                    } else if (kz < 153) {
                        const float wv = W_ih3[g * H1 + (kz - 102)];
                        v = wv - rbf(wv);
                    }
                }
                bf[j] = f2bf(v);
            }
            Zfr[kt] = bf;
        }
    }

    const float whh3_0 = W_hh3[0], whh3_1 = W_hh3[1];
    const float whh3_2 = W_hh3[2], whh3_3 = W_hh3[3];
    const float b3_0 = b_ih3[0] + b_hh3[0];
    const float b3_1 = b_ih3[1] + b_hh3[1];
    const float b3_2 = b_ih3[2] + b_hh3[2];
    const float b3_3 = b_ih3[3] + b_hh3[3];

    // ---- LDS init ----
    for (int idx = t; idx < 2 * MROW * PADK; idx += 512)
        ((short*)Hst)[idx] = 0;
    __syncthreads();   // ensure zeros before targeted writes
    if (t < MROW) {
        const int m = t;
#pragma unroll
        for (int p = 0; p < 2; ++p) {
            Hst[p][m * PADK + 156] = (short)0x3F80;   // 1.0
            Hst[p][m * PADK + 157] = (short)0x3F80;
        }
        const float x0 = input[(size_t)(r0 + m) * SEQT];
        const unsigned xp = pack_hilo(x0);
        Hst[1][m * PADK + 153] = (short)xp;   // window 0 reads parity 1
        Hst[1][m * PADK + 154] = (short)(xp >> 16);
        Hst[1][m * PADK + 155] = (short)xp;
    }
    if (w == 7) {                 // prefill x chunks 0 and 1 (only wave 7 reads Xbuf)
        xchunk_fill(input, r0, 0, lane, Xbuf);
        xchunk_fill(input, r0, 1, lane, Xbuf);
    }
    float c1st[2] = {0.f, 0.f};
    float h3 = 0.f, c3 = 0.f;   // LSTM3 state (wave 7, lanes 0..15 valid)

#pragma unroll 1
    for (int ts = 0; ts <= SEQT; ++ts) {
        __syncthreads();
        const int rb = (ts + 1) & 1, wb = ts & 1;

        // ---- B-frags: issue LDS reads first so latency overlaps step logic ----
        s16x8 hf[5];
        if (w < 7 && ts < SEQT) {
#pragma unroll
            for (int kt = 0; kt < 5; ++kt)
                hf[kt] = *(const s16x8*)&Hst[rb][iloc * PADK + kt * 32 + kq * 8];
        }
        s16x8 zf[5];
        if (w == 7 && ts >= 1) {
#pragma unroll
            for (int kt = 0; kt < 5; ++kt)
                zf[kt] = *(const s16x8*)
                    &Hst[rb][iloc * PADK + 160 + kt * 32 + kq * 8];
        }

        // ---- coalesced dump of finished 64-chunk (all 8 waves, 2 rows each) ----
        if (ts >= 65 && (ts & 63) == 1) {
            const int c = (ts >> 6) - 1;
#pragma unroll
            for (int rep = 0; rep < 2; ++rep) {
                const int row = w + 8 * rep;
                out[(size_t)(r0 + row) * SEQT + c * 64 + lane] =
                    Obuf[c & 1][row * 64 + lane];
            }
        }

        // ---- x chunk prefetch: issue loads early (consume at step bottom) ----
        const bool fill = (w == 7) && (ts < SEQT) && ((ts & 63) == 0) &&
                          (ts >= 64) && ((ts >> 6) < 31);
        const int fc = (ts >> 6) + 1;
        f32x4 xv[4];
        if (fill) {
            const int fm = lane & 15, fq = lane >> 4;
            const int tt = fc * 64 + fq * 16;
            if (tt < SEQT) {
                const float* src = input + (size_t)(r0 + fm) * SEQT + tt;
#pragma unroll
                for (int p = 0; p < 4; ++p) xv[p] = *(const f32x4*)(src + 4 * p);
            } else {
#pragma unroll
                for (int p = 0; p < 4; ++p) xv[p] = (f32x4){0.f, 0.f, 0.f, 0.f};
            }
        }

        if (ts < SEQT) {
            short* Hw = &Hst[wb][0];
            // ---- wave-specialized straight-line tile blocks ----
            if (w == 0) {
                run_tiles<0, 2>(Wfr, hf, c1st, Hw, iloc, kq);
            } else if (w == 1) {
                run_tiles<2, 2>(Wfr, hf, c1st, Hw, iloc, kq);
            } else if (w == 2) {
                run_tiles<4, 2>(Wfr, hf, c1st, Hw, iloc, kq);
            } else if (w == 3) {
                run_tiles<6, 2>(Wfr, hf, c1st, Hw, iloc, kq);
            } else if (w == 4) {
                run_tiles<8, 2>(Wfr, hf, c1st, Hw, iloc, kq);
            } else if (w == 5) {
                run_tiles<10, 2>(Wfr, hf, c1st, Hw, iloc, kq);
            } else if (w == 6) {
                run_tiles<12, 1>(Wfr, hf, c1st, Hw, iloc, kq);
            } else {
                // w7: x staging for step ts+1 from Xbuf (all lanes dup-write)
                const int t1 = ts + 1;
                if (t1 < SEQT) {
                    const int m2 = lane & 15;
                    const unsigned pv = Xbuf[(t1 >> 6) & 1][(t1 & 63) * 16 + m2];
                    Hw[m2 * PADK + 153] = (short)pv;
                    Hw[m2 * PADK + 154] = (short)(pv >> 16);
                    Hw[m2 * PADK + 155] = (short)pv;
                }
            }
        }

        // ---- z + LSTM3 for step ts-1 (wave 7; z-tile MFMA, kt 5..9) ----
        if (w == 7 && ts >= 1) {
            f32x4 z0 = {0.f, 0.f, 0.f, 0.f};
            f32x4 z1 = {0.f, 0.f, 0.f, 0.f};
            z0 = mfma16(Zfr[0], zf[0], z0);
            z1 = mfma16(Zfr[1], zf[1], z1);
            z0 = mfma16(Zfr[2], zf[2], z0);
            z1 = mfma16(Zfr[3], zf[3], z1);
            z0 = mfma16(Zfr[4], zf[4], z0);
            const f32x4 zacc = z0 + z1;
            // lanes 0..15 hold rows 0..3 = the 4 gates in regs; other lanes
            // compute bounded junk and never store.
            const int s = ts - 1;
            const float gi = zacc[0] + fmaf(whh3_0, h3, b3_0);
            const float gf = zacc[1] + fmaf(whh3_1, h3, b3_1);
            const float gg = zacc[2] + fmaf(whh3_2, h3, b3_2);
            const float go = zacc[3] + fmaf(whh3_3, h3, b3_3);
            c3 = sigf(gf) * c3 + sigf(gi) * tanhfast(gg);
            h3 = sigf(go) * tanhfast(c3);
            if (lane < MROW)
                Obuf[(s >> 6) & 1][(lane & 15) * 64 + (s & 63)] = c3;
        }

        // ---- x chunk prefetch: convert + store (loads had the step to land) ----
        if (fill) {
            const int fm = lane & 15, fq = lane >> 4;
#pragma unroll
            for (int p = 0; p < 4; ++p)
#pragma unroll
                for (int j = 0; j < 4; ++j)
                    Xbuf[fc & 1][(fq * 16 + p * 4 + j) * 16 + fm] =
                        pack_hilo(xv[p][j]);
        }
    }

    __syncthreads();
    // tail: steps 1984..1999 (chunk 31, parity 1)
    if (t < 256) {
        const int row = t >> 4, pos = t & 15;
        out[(size_t)(r0 + row) * SEQT + 1984 + pos] = Obuf[1][row * 64 + pos];
    }
}

extern "C" void kernel_launch(void* const* d_in, const int* in_sizes, int n_in,
                              void* d_out, int out_size, void* d_ws, size_t ws_size,
                              hipStream_t stream) {
    const float* input = (const float*)d_in[0];
    const float* W_ih1 = (const float*)d_in[1];
    const float* W_hh1 = (const float*)d_in[2];
    const float* b_ih1 = (const float*)d_in[3];
    const float* b_hh1 = (const float*)d_in[4];
    const float* W_ih3 = (const float*)d_in[5];
    const float* W_hh3 = (const float*)d_in[6];
    const float* b_ih3 = (const float*)d_in[7];
    const float* b_hh3 = (const float*)d_in[8];
    float* out = (float*)d_out;

    lstm_fused_kernel<<<NBLK, 512, 0, stream>>>(
        input, W_ih1, W_hh1, b_ih1, b_hh1, W_ih3, W_hh3, b_ih3, b_hh3, out);
}

// Round 3
// 2155.865 us; speedup vs baseline: 1.2963x; 1.2963x over previous
//
#include <hip/hip_runtime.h>
#include <hip/hip_bf16.h>

#define SEQT 2000
#define NB   2048
#define H1   51
#define MROW 16
#define NBLK (NB / MROW)   // 128 blocks
#define PADK 168           // shorts per staged row (336 B = 21*16, 16B-aligned)
#define OSTR 65            // Obuf row stride (floats) — odd, conflict-free

typedef float f32x4 __attribute__((ext_vector_type(4)));
typedef short s16x8 __attribute__((ext_vector_type(8)));

__device__ __forceinline__ short f2bf(float f) { __hip_bfloat16 b(f); return *(short*)&b; }
__device__ __forceinline__ float bf2f(short s) { __hip_bfloat16 b; *(short*)&b = s; return (float)b; }
__device__ __forceinline__ float rbf(float f) { return bf2f(f2bf(f)); }
__device__ __forceinline__ float fastrcp(float x) { return __builtin_amdgcn_rcpf(x); }
__device__ __forceinline__ float sigf(float x) { return fastrcp(1.f + __expf(-x)); }
__device__ __forceinline__ float tanhfast(float x) { return 1.f - 2.f * fastrcp(__expf(2.f * x) + 1.f); }

// RNE f32->bf16 (bit trick; values are finite so no NaN path needed)
__device__ __forceinline__ unsigned rne_bf16(float v) {
    unsigned b = __float_as_uint(v);
    return (b + 0x7fffu + ((b >> 16) & 1u)) >> 16;
}
// packed (hi | lo<<16), both RNE — used off the hot path (x staging)
__device__ __forceinline__ unsigned pack_hilo(float v) {
    const unsigned hh = rne_bf16(v);
    const float hi = __uint_as_float(hh << 16);
    const unsigned hl = rne_bf16(v - hi);
    return hh | (hl << 16);
}

__device__ __forceinline__ f32x4 mfma16(s16x8 a, s16x8 b, f32x4 c) {
    return __builtin_amdgcn_mfma_f32_16x16x32_bf16(a, b, c, 0, 0, 0);
}

// B-side (staged vector) column map, K=160 (5 k-tiles of 32):
//   2u/2u+1 (u<51): h_hi/h_lo      | A: Whh_hi[n][u] (both)
//   102+u   (u<51): h_hi           | A: Whh_lo[n][u]
//   153: x_hi  154: x_lo  155: x_hi| A: Wih_hi, Wih_hi, Wih_lo
//   156: 1.0   157: 1.0            | A: bias_hi, bias_lo
//   158,159: 0   160..167: write scratch (never read)
// Gate rows n' = u*4+g (13 N-tiles). MFMA A=weights, B=staged vector.
// C/D: col(lane&15)=m, row(quad*4+reg)=n' -> lane (kq,iloc) holds all 4 gates
// of unit u = tile*4+kq for batch row m = iloc.
// c1 is staged as raw f32 in C1buf[par][m*52+u]; LSTM3 (H3=1) consumes it via
// per-lane VALU dot products on wave 1 (no MFMA, no bf16 pack).
// Wave map (4 waves): w0 {0-3}, w2 {4-7}, w3 {8-11}, w1 {12} + z-dot + LSTM3 + x.

template <int I0, int NTc>
__device__ __forceinline__ void run_tiles(const s16x8 (&Wfr)[4][5], const s16x8 (&hf)[5],
                                          float (&c1st)[4], short* __restrict__ Hw,
                                          float* __restrict__ C1w,
                                          const int iloc, const int kq) {
    f32x4 acc[4];
#pragma unroll
    for (int i = 0; i < NTc; ++i) {
        f32x4 a0 = {0.f, 0.f, 0.f, 0.f};
        f32x4 a1 = {0.f, 0.f, 0.f, 0.f};
        a0 = mfma16(Wfr[i][0], hf[0], a0);
        a1 = mfma16(Wfr[i][1], hf[1], a1);
        a0 = mfma16(Wfr[i][2], hf[2], a0);
        a1 = mfma16(Wfr[i][3], hf[3], a1);
        a0 = mfma16(Wfr[i][4], hf[4], a0);
        acc[i] = a0 + a1;
    }
#pragma unroll
    for (int i = 0; i < NTc; ++i) {
        const int u = (I0 + i) * 4 + kq;
        const int m = iloc;
        float c1 = c1st[i];
        c1 = sigf(acc[i][1]) * c1 + sigf(acc[i][0]) * tanhfast(acc[i][2]);
        c1st[i] = c1;
        const float h1 = sigf(acc[i][3]) * tanhfast(c1);
        const bool ok = (u < H1);
        // RTZ hi + RNE lo: same 2^-17 combined error, 4 fewer VALU ops
        const unsigned uv = __float_as_uint(h1);
        const unsigned hh = uv >> 16;
        const float hif = __uint_as_float(uv & 0xffff0000u);
        const unsigned ll = rne_bf16(h1 - hif);
        const unsigned hp = hh | (ll << 16);
        const int base = m * PADK;
        *(unsigned*)&Hw[base + (ok ? 2 * u : 160)] = hp;
        Hw[base + (ok ? 102 + u : 164)] = (short)hp;
        C1w[m * 52 + (ok ? u : 51)] = c1;   // raw f32; col 51 = scratch (W=0)
    }
}

// Fill one 64-step x-chunk into Xbuf (wave 1, all 64 lanes).
__device__ __forceinline__ void xchunk_fill(const float* __restrict__ input, int r0, int c,
                                            int lane, unsigned (*Xb)[64 * 16]) {
    const int m = lane & 15, q = lane >> 4;
    const int tt = c * 64 + q * 16;
    f32x4 v[4];
    if (tt < SEQT) {
        const float* src = input + (size_t)(r0 + m) * SEQT + tt;
#pragma unroll
        for (int p = 0; p < 4; ++p) v[p] = *(const f32x4*)(src + 4 * p);
    } else {
#pragma unroll
        for (int p = 0; p < 4; ++p) v[p] = (f32x4){0.f, 0.f, 0.f, 0.f};
    }
#pragma unroll
    for (int p = 0; p < 4; ++p)
#pragma unroll
        for (int j = 0; j < 4; ++j)
            Xb[c & 1][(q * 16 + p * 4 + j) * 16 + m] = pack_hilo(v[p][j]);
}

__global__ void __launch_bounds__(256)
__attribute__((amdgpu_waves_per_eu(1)))
lstm_fused_kernel(const float* __restrict__ input,
                  const float* __restrict__ W_ih1,
                  const float* __restrict__ W_hh1,
                  const float* __restrict__ b_ih1,
                  const float* __restrict__ b_hh1,
                  const float* __restrict__ W_ih3,
                  const float* __restrict__ W_hh3,
                  const float* __restrict__ b_ih3,
                  const float* __restrict__ b_hh3,
                  float* __restrict__ out) {
    const int t = threadIdx.x;
    const int w = t >> 6;          // wave 0..3
    const int lane = t & 63;
    const int iloc = lane & 15, kq = lane >> 4;
    const int r0 = blockIdx.x * MROW;

    __shared__ short Hst[2][MROW * PADK];      // staged h/x/bias rows, parity dbuf
    __shared__ float C1buf[2][MROW * 52];      // raw f32 c1, parity dbuf
    __shared__ float Obuf[2][MROW * OSTR];     // c3 chunks
    __shared__ unsigned Xbuf[2][64 * 16];      // packed x hi/lo, 64-step chunks
    __shared__ float Ztr[MROW * 4];            // LSTM3 gate-activation transpose

    // tile assignment: w0 {0-3}, w1 {12}, w2 {4-7}, w3 {8-11}
    const int NT = (w == 1) ? 1 : 4;
    const int tb = (w == 0) ? 0 : (w == 1) ? 12 : (w == 2) ? 4 : 8;

    // ---- gate-row weight fragments (A-operand) ----
    s16x8 Wfr[4][5];
#pragma unroll
    for (int i = 0; i < 4; ++i) {
        if (i < NT) {
            const int np = (tb + i) * 16 + iloc;
            const int u = np >> 2, g = np & 3;
            const int n = g * H1 + u;
#pragma unroll
            for (int kt = 0; kt < 5; ++kt) {
                s16x8 bf;
#pragma unroll
                for (int j = 0; j < 8; ++j) {
                    const int k = kt * 32 + kq * 8 + j;
                    float v = 0.f;
                    if (u < H1) {
                        if (k < 102) {
                            v = rbf(W_hh1[n * H1 + (k >> 1)]);
                        } else if (k < 153) {
                            const float wv = W_hh1[n * H1 + (k - 102)];
                            v = wv - rbf(wv);
                        } else if (k == 153 || k == 154) {
                            v = rbf(W_ih1[n]);
                        } else if (k == 155) {
                            const float wv = W_ih1[n];
                            v = wv - rbf(wv);
                        } else if (k == 156) {
                            v = rbf(b_ih1[n] + b_hh1[n]);
                        } else if (k == 157) {
                            const float bv = b_ih1[n] + b_hh1[n];
                            v = bv - rbf(bv);
                        }
                    }
                    bf[j] = f2bf(v);
                }
                Wfr[i][kt] = bf;
            }
        }
    }

    // ---- wave 1: LSTM3 constants. lane (m,g): m = lane&15, g = lane>>4 ----
    const int g3 = lane >> 4;
    float Wz[52];
    if (w == 1) {
#pragma unroll
        for (int j = 0; j < 52; ++j)
            Wz[j] = (j < H1) ? W_ih3[g3 * H1 + j] : 0.f;
    }
    const float whh3g = W_hh3[g3];
    const float b3g = b_ih3[g3] + b_hh3[g3];
    // activation form: act = bg + ag * rcp(exp(kg*x)+1)
    const float kg = (g3 == 2) ? 2.f : -1.f;
    const float ag = (g3 == 2) ? -2.f : 1.f;
    const float bg = (g3 == 2) ? 1.f : 0.f;

    // ---- LDS init ----
    for (int idx = t; idx < 2 * MROW * PADK; idx += 256)
        ((short*)Hst)[idx] = 0;
    for (int idx = t; idx < 2 * MROW * 52; idx += 256)
        ((float*)C1buf)[idx] = 0.f;
    __syncthreads();   // ensure zeros before targeted writes
    if (t < MROW) {
        const int m = t;
#pragma unroll
        for (int p = 0; p < 2; ++p) {
            Hst[p][m * PADK + 156] = (short)0x3F80;   // 1.0
            Hst[p][m * PADK + 157] = (short)0x3F80;
        }
        const float x0 = input[(size_t)(r0 + m) * SEQT];
        const unsigned xp = pack_hilo(x0);
        Hst[1][m * PADK + 153] = (short)xp;   // window 0 reads parity 1
        Hst[1][m * PADK + 154] = (short)(xp >> 16);
        Hst[1][m * PADK + 155] = (short)xp;
    }
    if (w == 1) {                 // prefill x chunks 0 and 1 (only wave 1 reads Xbuf)
        xchunk_fill(input, r0, 0, lane, Xbuf);
        xchunk_fill(input, r0, 1, lane, Xbuf);
    }
    float c1st[4] = {0.f, 0.f, 0.f, 0.f};
    float h3 = 0.f, c3 = 0.f;   // LSTM3 state (wave 1, lanes 0..15 valid)
    float h3b = 0.f;            // h3 broadcast to all 64 lanes (per m)

#pragma unroll 1
    for (int ts = 0; ts <= SEQT; ++ts) {
        __syncthreads();
        const int rb = (ts + 1) & 1, wb = ts & 1;

        // ---- B-frags first: LDS read latency overlaps everything below ----
        s16x8 hf[5];
        if (ts < SEQT) {
#pragma unroll
            for (int kt = 0; kt < 5; ++kt)
                hf[kt] = *(const s16x8*)&Hst[rb][iloc * PADK + kt * 32 + kq * 8];
        }
        // ---- wave 1: c1 row reads (broadcast across the 4 gate-lanes) ----
        f32x4 c1v[13];
        if (w == 1 && ts >= 1) {
            const float* cr = &C1buf[rb][(lane & 15) * 52];
#pragma unroll
            for (int j = 0; j < 13; ++j)
                c1v[j] = *(const f32x4*)(cr + 4 * j);
        }

        // ---- coalesced dump of finished 64-chunk ----
        if (ts >= 65 && (ts & 63) == 1) {
            const int c = (ts >> 6) - 1;
#pragma unroll
            for (int rep = 0; rep < 4; ++rep) {
                const int row = w + 4 * rep;
                out[(size_t)(r0 + row) * SEQT + c * 64 + lane] =
                    Obuf[c & 1][row * OSTR + lane];
            }
        }

        // ---- x chunk prefetch: issue loads early (consume at step bottom) ----
        const bool fill = (w == 1) && (ts < SEQT) && ((ts & 63) == 0) &&
                          (ts >= 64) && ((ts >> 6) < 31);
        const int fc = (ts >> 6) + 1;
        f32x4 xv[4];
        if (fill) {
            const int fm = lane & 15, fq = lane >> 4;
            const int tt = fc * 64 + fq * 16;
            if (tt < SEQT) {
                const float* src = input + (size_t)(r0 + fm) * SEQT + tt;
#pragma unroll
                for (int p = 0; p < 4; ++p) xv[p] = *(const f32x4*)(src + 4 * p);
            } else {
#pragma unroll
                for (int p = 0; p < 4; ++p) xv[p] = (f32x4){0.f, 0.f, 0.f, 0.f};
            }
        }

        if (ts < SEQT) {
            short* Hw = &Hst[wb][0];
            float* C1w = &C1buf[wb][0];
            if (w == 0) {
                run_tiles<0, 4>(Wfr, hf, c1st, Hw, C1w, iloc, kq);
            } else if (w == 2) {
                run_tiles<4, 4>(Wfr, hf, c1st, Hw, C1w, iloc, kq);
            } else if (w == 3) {
                run_tiles<8, 4>(Wfr, hf, c1st, Hw, C1w, iloc, kq);
            } else {
                // w1: x staging for step ts+1 from Xbuf (lanes dup-write)
                const int t1 = ts + 1;
                if (t1 < SEQT) {
                    const int m2 = lane & 15;
                    const unsigned pv = Xbuf[(t1 >> 6) & 1][(t1 & 63) * 16 + m2];
                    Hw[m2 * PADK + 153] = (short)pv;
                    Hw[m2 * PADK + 154] = (short)(pv >> 16);
                    Hw[m2 * PADK + 155] = (short)pv;
                }
                run_tiles<12, 1>(Wfr, hf, c1st, Hw, C1w, iloc, kq);
            }
        }

        // ---- LSTM3 for step ts-1 (wave 1): VALU dot + 64-lane activations ----
        if (w == 1 && ts >= 1) {
            float d0 = 0.f, d1 = 0.f, d2 = 0.f, d3 = 0.f;
#pragma unroll
            for (int j = 0; j < 13; ++j) {
                d0 = fmaf(Wz[4 * j + 0], c1v[j][0], d0);
                d1 = fmaf(Wz[4 * j + 1], c1v[j][1], d1);
                d2 = fmaf(Wz[4 * j + 2], c1v[j][2], d2);
                d3 = fmaf(Wz[4 * j + 3], c1v[j][3], d3);
            }
            const float z = (d0 + d1) + (d2 + d3);
            // lane (m,g): pre-activation and activation for its own gate
            const float pre = z + fmaf(whh3g, h3b, b3g);
            const float act = bg + ag * fastrcp(__expf(kg * pre) + 1.f);
            // transpose gate-activations: lane (m,g) -> Ztr[m*4+g]
            Ztr[(lane & 15) * 4 + g3] = act;
            __builtin_amdgcn_wave_barrier();   // compile-time: keep write before read
            const int s = ts - 1;
            if (lane < MROW) {
                const f32x4 a4 = *(const f32x4*)&Ztr[lane * 4];   // i,f,g,o
                c3 = a4[1] * c3 + a4[0] * a4[2];
                h3 = a4[3] * tanhfast(c3);
                Obuf[(s >> 6) & 1][lane * OSTR + (s & 63)] = c3;
            }
            h3b = __shfl(h3, lane & 15, 64);
        }

        // ---- x chunk prefetch: convert + store (loads had the step to land) ----
        if (fill) {
            const int fm = lane & 15, fq = lane >> 4;
#pragma unroll
            for (int p = 0; p < 4; ++p)
#pragma unroll
                for (int j = 0; j < 4; ++j)
                    Xbuf[fc & 1][(fq * 16 + p * 4 + j) * 16 + fm] =
                        pack_hilo(xv[p][j]);
        }
    }

    __syncthreads();
    // tail: steps 1984..1999 (chunk 31, parity 1)
    {
        const int row = t >> 4, pos = t & 15;
        out[(size_t)(r0 + row) * SEQT + 1984 + pos] = Obuf[1][row * OSTR + pos];
    }
}

extern "C" void kernel_launch(void* const* d_in, const int* in_sizes, int n_in,
                              void* d_out, int out_size, void* d_ws, size_t ws_size,
                              hipStream_t stream) {
    const float* input = (const float*)d_in[0];
    const float* W_ih1 = (const float*)d_in[1];
    const float* W_hh1 = (const float*)d_in[2];
    const float* b_ih1 = (const float*)d_in[3];
    const float* b_hh1 = (const float*)d_in[4];
    const float* W_ih3 = (const float*)d_in[5];
    const float* W_hh3 = (const float*)d_in[6];
    const float* b_ih3 = (const float*)d_in[7];
    const float* b_hh3 = (const float*)d_in[8];
    float* out = (float*)d_out;

    lstm_fused_kernel<<<NBLK, 256, 0, stream>>>(
        input, W_ih1, W_hh1, b_ih1, b_hh1, W_ih3, W_hh3, b_ih3, b_hh3, out);
}